// Round 2
// baseline (992.350 us; speedup 1.0000x reference)
//
#include <hip/hip_runtime.h>

typedef unsigned short u16;
typedef __bf16 bf16x8 __attribute__((ext_vector_type(8)));
typedef float f32x4 __attribute__((ext_vector_type(4)));

#define D_MODEL 256
#define D_INNER 1024
#define NST     16
#define SEQ     2048
#define LOG2E   1.4426950408889634f

struct TrueT  { static constexpr bool value = true;  };
struct FalseT { static constexpr bool value = false; };

static __device__ __forceinline__ float bf2f(u16 u) {
    union { float f; unsigned v; } x; x.v = ((unsigned)u) << 16; return x.f;
}
static __device__ __forceinline__ u16 f2bf(float f) {
    union { float f; unsigned u; } x; x.f = f;
    unsigned r = 0x7FFF + ((x.u >> 16) & 1);
    return (u16)((x.u + r) >> 16);
}

// async global->LDS, 16B per lane, LDS dest = wave-uniform base + lane*16
#define GLOAD_LDS16(g, l)                                            \
    __builtin_amdgcn_global_load_lds(                                \
        (const __attribute__((address_space(1))) void*)(g),          \
        (__attribute__((address_space(3))) void*)(l), 16, 0, 0)

// dA[n] = e1^(n+1), n=0..15, via binary decomposition (16 muls, depth ~5)
static __device__ __forceinline__ void dA_pow(float e1, float* dA) {
    float e2 = e1 * e1, e3 = e2 * e1, e4 = e2 * e2;
    float e8 = e4 * e4, e12 = e8 * e4;
    dA[0] = e1;       dA[1] = e2;       dA[2] = e3;       dA[3] = e4;
    dA[4] = e4 * e1;  dA[5] = e4 * e2;  dA[6] = e4 * e3;  dA[7] = e8;
    dA[8] = e8 * e1;  dA[9] = e8 * e2;  dA[10] = e8 * e3; dA[11] = e12;
    dA[12] = e12 * e1; dA[13] = e12 * e2; dA[14] = e12 * e3; dA[15] = e8 * e8;
}

// ---- RMSNorm -> split-bf16 pair output: row = [256 hi | 256 lo] u16 ----
__global__ __launch_bounds__(256) void rmsnorm_k(const float* __restrict__ x,
                                                 const float* __restrict__ w,
                                                 u16* __restrict__ xnp) {
    int row = blockIdx.x, t = threadIdx.x;
    float v = x[(size_t)row * D_MODEL + t];
    float s = v * v;
    #pragma unroll
    for (int o = 32; o; o >>= 1) s += __shfl_xor(s, o, 64);
    __shared__ float red[4];
    if ((t & 63) == 0) red[t >> 6] = s;
    __syncthreads();
    float tot = red[0] + red[1] + red[2] + red[3];
    float scale = rsqrtf(tot * (1.0f / D_MODEL) + 1e-5f);
    float xv = v * scale * w[t];
    u16 hi = f2bf(xv);
    u16 lo = f2bf(xv - bf2f(hi));
    xnp[(size_t)row * 512 + t] = hi;
    xnp[(size_t)row * 512 + 256 + t] = lo;
}

// ---- weight split: src[N*K] f32 -> dst[N][2K] bf16 (hi | lo) -----------
__global__ __launch_bounds__(256) void wsplit_k(const float* __restrict__ src,
                                                u16* __restrict__ dst, int K) {
    int i = blockIdx.x * 256 + threadIdx.x;
    int n = i / K, k = i - n * K;
    float v = src[i];
    u16 hi = f2bf(v);
    u16 lo = f2bf(v - bf2f(hi));
    dst[(size_t)n * 2 * K + k] = hi;
    dst[(size_t)n * 2 * K + K + k] = lo;
}

// ---- weight split with zero-padded rows (for x_proj: 48 real -> 128) ----
__global__ __launch_bounds__(256) void wsplit_pad_k(const float* __restrict__ src,
                                                    u16* __restrict__ dst, int K,
                                                    int Nreal) {
    int i = blockIdx.x * 256 + threadIdx.x;
    int n = i / K, k = i - n * K;
    float v = 0.0f;
    if (n < Nreal) v = src[i];
    u16 hi = f2bf(v);
    u16 lo = f2bf(v - bf2f(hi));
    dst[(size_t)n * 2 * K + k] = hi;
    dst[(size_t)n * 2 * K + K + k] = lo;
}

// ---- split-bf16 MFMA GEMM, 128x128 tile (kept for x_proj, N=48 masked) --
__global__ __launch_bounds__(256) void gemm_mfma(const u16* __restrict__ Ap, int lda,
                                                 const u16* __restrict__ Wp, int ldw,
                                                 float* __restrict__ C, int ldc,
                                                 int KL, int kslice, size_t zstride,
                                                 int Nreal) {
    __shared__ u16 As[128][64];
    __shared__ u16 Ws[128][64];
    const int m0 = blockIdx.x * 128, n0 = blockIdx.y * 128;
    const int tid = threadIdx.x;
    const int wave = tid >> 6, lane = tid & 63;
    const int wm = (wave >> 1) * 64, wn = (wave & 1) * 64;
    const int lm = lane & 15, quad = lane >> 4;

    const int srow = lane >> 3;                // == row & 7
    const int schunk = (lane & 7) ^ srow;      // swizzled source 16B chunk
    const int rloc = wave * 8 + srow;

    f32x4 acc[4][4] = {};

    const int kb0 = blockIdx.z * kslice;
    for (int k0 = kb0; k0 < kb0 + kslice; k0 += 64) {
        int t = k0 / KL;
        int ko = k0 - t * KL;
        int ka = ko + (t == 2 ? KL : 0) + schunk * 8;
        int kw = ko + (t == 1 ? KL : 0) + schunk * 8;
        #pragma unroll
        for (int p = 0; p < 4; p++) {
            int row = p * 32 + rloc;
            GLOAD_LDS16(Ap + (size_t)(m0 + row) * lda + ka,
                        &As[p * 32 + wave * 8][0]);
            GLOAD_LDS16(Wp + (size_t)(n0 + row) * ldw + kw,
                        &Ws[p * 32 + wave * 8][0]);
        }
        __syncthreads();
        const int sc = lm & 7;
        #pragma unroll
        for (int kk = 0; kk < 2; kk++) {
            const int ch = ((kk << 2) | quad) ^ sc;   // undo swizzle
            bf16x8 af[4], bv[4];
            #pragma unroll
            for (int i = 0; i < 4; i++)
                af[i] = *(const bf16x8*)&As[wm + i * 16 + lm][ch * 8];
            #pragma unroll
            for (int j = 0; j < 4; j++)
                bv[j] = *(const bf16x8*)&Ws[wn + j * 16 + lm][ch * 8];
            #pragma unroll
            for (int i = 0; i < 4; i++)
                #pragma unroll
                for (int j = 0; j < 4; j++)
                    acc[i][j] = __builtin_amdgcn_mfma_f32_16x16x32_bf16(
                        af[i], bv[j], acc[i][j], 0, 0, 0);
        }
        __syncthreads();
    }

    float* Cz = C + zstride * blockIdx.z;
    #pragma unroll
    for (int i = 0; i < 4; i++)
        #pragma unroll
        for (int j = 0; j < 4; j++)
            #pragma unroll
            for (int r = 0; r < 4; r++) {
                int mrow = m0 + wm + i * 16 + quad * 4 + r;
                int ncol = n0 + wn + j * 16 + lm;
                if (ncol < Nreal)
                    Cz[(size_t)mrow * ldc + ncol] = acc[i][j][r];
            }
}

// ---- 256x256 tile, BK=32, 8-wave, 3-deep LDS ring, counted vmcnt --------
// T3+T4 schedule: while computing tile t (2 phases), tile t+1 is landed and
// tile t+2 is in flight (4 loads/thread). End-of-tile s_waitcnt vmcnt(4)
// guarantees t+1 landed (in-order vmem retirement) without draining t+2.
// LDS rows are 64B (32 u16); reads use chunk ^= (row&3), applied inversely
// on the global source (LDS dest of global_load_lds must stay linear).
// Requires: kslice % 32 == 0, NT = kslice/32 >= 2, M % 256 == 0,
//           Wp has >= gridDim.y*256 valid rows.
__global__ __launch_bounds__(512, 2) void gemm_mfma2(const u16* __restrict__ Ap, int lda,
                                                     const u16* __restrict__ Wp, int ldw,
                                                     float* __restrict__ C, int ldc,
                                                     int KL, int kslice, size_t zstride,
                                                     int Nreal) {
    __shared__ u16 As[3][256][32];
    __shared__ u16 Ws[3][256][32];
    const int m0 = blockIdx.x * 256, n0 = blockIdx.y * 256;
    const int tid = threadIdx.x;
    const int wave = tid >> 6, lane = tid & 63;
    const int wm = (wave >> 2) * 128, wn = (wave & 3) * 64;
    const int lm = lane & 15, quad = lane >> 4;

    // staging: per instr, wave covers 16 rows x 64B; lane -> row wave*16+(lane>>2),
    // 16B chunk (lane&3), source chunk XOR-swizzled by row&3.
    const int srow = lane >> 2;
    const int schunk = (lane & 3) ^ (srow & 3);
    const int KL2 = 2 * KL;

    const int NT = kslice / 32;
    const int kb0 = blockIdx.z * kslice;

    const u16* Arow = Ap + (size_t)(m0 + wave * 16 + srow) * lda + schunk * 8;
    const u16* Wrow = Wp + (size_t)(n0 + wave * 16 + srow) * ldw + schunk * 8;
    const size_t ldA = (size_t)128 * lda;
    const size_t ldW = (size_t)128 * ldw;
    u16* AsW = &As[0][wave * 16][0];   // + buf*8192 + half*4096
    u16* WsW = &Ws[0][wave * 16][0];

    f32x4 acc[8][4] = {};

    // k-offsets for tile ts (absolute k = kb0 + ts*32)
    auto koffs = [&](int ts, int& ka, int& kw) {
        int ks = kb0 + ts * 32;
        int t = (ks >= KL2) ? 2 : (ks >= KL ? 1 : 0);
        int ko = ks - t * KL;
        ka = ko + (t == 2 ? KL : 0);
        kw = ko + (t == 1 ? KL : 0);
    };

    // prologue: stage tiles 0 and 1 (grouped per tile for vmcnt counting)
    {
        int ka, kw;
        koffs(0, ka, kw);
        GLOAD_LDS16(Arow + ka, AsW);
        GLOAD_LDS16(Arow + ldA + ka, AsW + 4096);
        GLOAD_LDS16(Wrow + kw, WsW);
        GLOAD_LDS16(Wrow + ldW + kw, WsW + 4096);
        koffs(1, ka, kw);
        GLOAD_LDS16(Arow + ka, AsW + 8192);
        GLOAD_LDS16(Arow + ldA + ka, AsW + 8192 + 4096);
        GLOAD_LDS16(Wrow + kw, WsW + 8192);
        GLOAD_LDS16(Wrow + ldW + kw, WsW + 8192 + 4096);
    }
    asm volatile("s_waitcnt vmcnt(4)" ::: "memory");   // tile 0 landed
    __syncthreads();

    int cur = 0, stg = 2;                               // tt%3, (tt+2)%3
    const int rdsw = (quad ^ (lm & 3)) * 8;             // read chunk swizzle base? no:
    for (int tt = 0; tt < NT; ++tt) {
        const u16* Ab = &As[cur][0][0];
        const u16* Wb = &Ws[cur][0][0];
        const bool pre = (tt + 2 < NT);
        int ka = 0, kw = 0;
        if (pre) koffs(tt + 2, ka, kw);

        bf16x8 bv[4], af[4];
        // ---- phase A: read B(all) + A frags 0..3; stage (tt+2) A halves ----
        #pragma unroll
        for (int j = 0; j < 4; j++) {
            int r = wn + j * 16 + lm;
            bv[j] = *(const bf16x8*)(Wb + r * 32 + ((quad ^ (r & 3)) * 8));
        }
        #pragma unroll
        for (int i = 0; i < 4; i++) {
            int r = wm + i * 16 + lm;
            af[i] = *(const bf16x8*)(Ab + r * 32 + ((quad ^ (r & 3)) * 8));
        }
        if (pre) {
            GLOAD_LDS16(Arow + ka, AsW + stg * 8192);
            GLOAD_LDS16(Arow + ldA + ka, AsW + stg * 8192 + 4096);
        }
        __syncthreads();
        __builtin_amdgcn_s_setprio(1);
        #pragma unroll
        for (int i = 0; i < 4; i++)
            #pragma unroll
            for (int j = 0; j < 4; j++)
                acc[i][j] = __builtin_amdgcn_mfma_f32_16x16x32_bf16(
                    af[i], bv[j], acc[i][j], 0, 0, 0);
        __builtin_amdgcn_s_setprio(0);
        __syncthreads();

        // ---- phase B: read A frags 4..7; stage (tt+2) W halves ----
        #pragma unroll
        for (int i = 0; i < 4; i++) {
            int r = wm + 64 + i * 16 + lm;
            af[i] = *(const bf16x8*)(Ab + r * 32 + ((quad ^ (r & 3)) * 8));
        }
        if (pre) {
            GLOAD_LDS16(Wrow + kw, WsW + stg * 8192);
            GLOAD_LDS16(Wrow + ldW + kw, WsW + stg * 8192 + 4096);
        }
        __syncthreads();
        __builtin_amdgcn_s_setprio(1);
        #pragma unroll
        for (int i = 0; i < 4; i++)
            #pragma unroll
            for (int j = 0; j < 4; j++)
                acc[4 + i][j] = __builtin_amdgcn_mfma_f32_16x16x32_bf16(
                    af[i], bv[j], acc[4 + i][j], 0, 0, 0);
        __builtin_amdgcn_s_setprio(0);
        // counted wait: all but tile (tt+2)'s 4 loads have landed => t+1 ready
        if (pre) asm volatile("s_waitcnt vmcnt(4)" ::: "memory");
        else     asm volatile("s_waitcnt vmcnt(0)" ::: "memory");
        __syncthreads();

        cur = (cur == 2) ? 0 : cur + 1;
        stg = (stg == 2) ? 0 : stg + 1;
    }
    (void)rdsw;

    float* Cz = C + zstride * blockIdx.z;
    #pragma unroll
    for (int i = 0; i < 8; i++)
        #pragma unroll
        for (int j = 0; j < 4; j++)
            #pragma unroll
            for (int r = 0; r < 4; r++) {
                int mrow = m0 + wm + i * 16 + quad * 4 + r;
                int ncol = n0 + wn + j * 16 + lm;
                if (ncol < Nreal)
                    Cz[(size_t)mrow * ldc + ncol] = acc[i][j][r];
            }
}

// ------ reduce 8 x_proj partials -> dbl[R*48] -----------------------------
__global__ __launch_bounds__(256) void reduce_dbl_k(const float* __restrict__ pbuf,
                                                    float* __restrict__ dbl,
                                                    size_t RS) {
    size_t e = (size_t)blockIdx.x * 256 + threadIdx.x;
    float v = 0.0f;
    #pragma unroll
    for (int z = 0; z < 8; z++) v += pbuf[z * RS + e];
    dbl[e] = v;
}

// ------ reduce 4 out_proj partials + residual -> out[m, coff + n] ---------
__global__ __launch_bounds__(256) void reduce_out_k(const float* __restrict__ pbuf,
                                                    const float* __restrict__ res,
                                                    float* __restrict__ out,
                                                    int M, int coff) {
    int idx = blockIdx.x * 256 + threadIdx.x;
    int m = idx >> 6, n4 = (idx & 63) * 4;
    size_t e = (size_t)m * 256 + n4;
    size_t stride = (size_t)M * 256;
    float4 v = *(const float4*)(res + e);
    #pragma unroll
    for (int s = 0; s < 4; s++) {
        float4 p = *(const float4*)(pbuf + s * stride + e);
        v.x += p.x; v.y += p.y; v.z += p.z; v.w += p.w;
    }
    *(float4*)(out + (size_t)m * 512 + coff + n4) = v;
}

// ---- depthwise causal conv + SiLU; out = split-bf16 pair ----------------
__global__ __launch_bounds__(256) void conv_silu_k(const float* __restrict__ xz,
                                                   const float* __restrict__ cw,
                                                   const float* __restrict__ cb,
                                                   u16* __restrict__ xcp, int dir) {
    int bx = blockIdx.x;
    int dgrp = bx & 3;
    int rowgrp = bx >> 2;
    int l0 = (rowgrp & (SEQ / 4 - 1)) * 4;
    int b = rowgrp >> 9;
    int d = dgrp * 256 + threadIdx.x;

    int base = dir ? l0 : (l0 - 3);
    float x[7];
    #pragma unroll
    for (int i = 0; i < 7; i++) {
        int lr = base + i;
        x[i] = (lr >= 0 && lr < SEQ)
             ? xz[((size_t)b * SEQ + lr) * (2 * D_INNER) + d] : 0.0f;
    }
    float w0 = cw[d * 4 + 0], w1 = cw[d * 4 + 1];
    float w2 = cw[d * 4 + 2], w3 = cw[d * 4 + 3];
    float bias = cb[d];

    #pragma unroll
    for (int li = 0; li < 4; li++) {
        float acc;
        if (dir == 0)
            acc = bias + w0 * x[li] + w1 * x[li + 1] + w2 * x[li + 2] + w3 * x[li + 3];
        else
            acc = bias + w3 * x[li] + w2 * x[li + 1] + w1 * x[li + 2] + w0 * x[li + 3];
        float s = acc / (1.0f + __expf(-acc));
        u16 hi = f2bf(s);
        u16 lo = f2bf(s - bf2f(hi));
        size_t row = (size_t)b * SEQ + l0 + li;
        xcp[row * 2048 + d] = hi;
        xcp[row * 2048 + D_INNER + d] = lo;
    }
}

// ---- scan phase 1: per-chunk H (h_in=0) and P; dbl staged in LDS --------
__global__ __launch_bounds__(256) void scan_p1(const u16* __restrict__ xcp,
                                               const float* __restrict__ dbl,
                                               const float* __restrict__ dtw,
                                               const float* __restrict__ dtb,
                                               const float* __restrict__ Alog,
                                               float* __restrict__ P,
                                               float* __restrict__ H,
                                               int nb, int TC, int dir) {
    __shared__ float sdbl[32 * 48];            // TC <= 32
    int t = threadIdx.x;
    int nblk4 = nb * 4;
    int c = blockIdx.x / nblk4;
    int rem = blockIdx.x - c * nblk4;
    int b = rem >> 2, dblk = rem & 3;
    int d = dblk * 256 + t;

    int lbase = dir ? (SEQ - (c + 1) * TC) : (c * TC);
    {
        const float* src = dbl + ((size_t)b * SEQ + lbase) * 48;
        int nf4 = TC * 12;
        for (int i = t; i < nf4; i += 256)
            *(float4*)&sdbl[i * 4] = *(const float4*)(src + i * 4);
    }

    float A2[16], wdt[16];
    const float* ap = Alog + (size_t)d * NST;
    const float* wp = dtw + (size_t)d * NST;
    #pragma unroll
    for (int n = 0; n < 16; n++) { A2[n] = -__expf(ap[n]) * LOG2E; wdt[n] = wp[n]; }
    float bdt = dtb[d];
    bool fast = true;
    #pragma unroll
    for (int n = 0; n < 16; n++)
        fast = fast && (fabsf(A2[n] - (n + 1) * A2[0]) < 1e-3f);

    float h[16] = {0,0,0,0,0,0,0,0,0,0,0,0,0,0,0,0};
    float S = 0.0f;

    int lstep = dir ? -1 : 1;
    int l0 = dir ? (lbase + TC - 1) : lbase;
    const u16* up = xcp + ((size_t)b * SEQ + l0) * 2048 + d;
    ptrdiff_t ups = (ptrdiff_t)lstep * 2048;
    const float* dr = sdbl + (dir ? (TC - 1) * 48 : 0);
    ptrdiff_t drs = (ptrdiff_t)lstep * 48;

    __syncthreads();

    auto body = [&](auto FC) {
        constexpr bool F = decltype(FC)::value;
        #pragma unroll 2
        for (int s = 0; s < TC; s++) {
            float dl[16], B[16];
            #pragma unroll
            for (int n = 0; n < 16; n += 4) {
                *(float4*)&dl[n] = *(const float4*)(dr + n);
                *(float4*)&B[n]  = *(const float4*)(dr + 16 + n);
            }
            float u = bf2f(up[0]) + bf2f(up[D_INNER]);
            float acc = bdt;
            #pragma unroll
            for (int n = 0; n < 16; n++) acc += dl[n] * wdt[n];
            float dt = (acc > 20.0f) ? acc : __logf(1.0f + __expf(acc));
            float dtu = dt * u;
            S += dt;
            float dA[16];
            if (F) {
                dA_pow(exp2f(A2[0] * dt), dA);
            } else {
                #pragma unroll
                for (int n = 0; n < 16; n++) dA[n] = exp2f(A2[n] * dt);
            }
            #pragma unroll
            for (int n = 0; n < 16; n++)
                h[n] = h[n] * dA[n] + dtu * B[n];
            dr += drs; up += ups;
        }
    };
    if (fast) body(TrueT{}); else body(FalseT{});

    size_t NCH = (size_t)nb * 16384;
    size_t base = (size_t)c * NCH + ((size_t)b * 1024 + d) * 16;
    float Pv[16];
    if (fast) {
        dA_pow(exp2f(A2[0] * S), Pv);
    } else {
        #pragma unroll
        for (int n = 0; n < 16; n++) Pv[n] = exp2f(A2[n] * S);
    }
    #pragma unroll
    for (int n = 0; n < 16; n += 4) {
        *(float4*)&H[base + n] = *(float4*)&h[n];
        *(float4*)&P[base + n] = *(float4*)&Pv[n];
    }
}

// ------- scan phase 2: combine chunk states; H repurposed as h_in --------
__global__ __launch_bounds__(256) void scan_p2(const float* __restrict__ P,
                                               float* __restrict__ H,
                                               int NCH, int NC) {
    size_t chain = (size_t)blockIdx.x * 256 + threadIdx.x;
    float h = 0.0f;
    for (int c = 0; c < NC; c++) {
        size_t i = (size_t)c * NCH + chain;
        float Hc = H[i], Pc = P[i];
        H[i] = h;
        h = Hc + Pc * h;
    }
}

// ---- scan phase 3: recurrence + silu(z) + y pair; dbl staged in LDS -----
__global__ __launch_bounds__(256) void scan_p3(const u16* __restrict__ xcp,
                                               const float* __restrict__ dbl,
                                               const float* __restrict__ dtw,
                                               const float* __restrict__ dtb,
                                               float* __restrict__ xz,
                                               const float* __restrict__ Alog,
                                               const float* __restrict__ Dp,
                                               const float* __restrict__ hin,
                                               int nb, int TC, int dir) {
    __shared__ float sdbl[32 * 48];
    int t = threadIdx.x;
    int nblk4 = nb * 4;
    int c = blockIdx.x / nblk4;
    int rem = blockIdx.x - c * nblk4;
    int b = rem >> 2, dblk = rem & 3;
    int d = dblk * 256 + t;

    int lbase = dir ? (SEQ - (c + 1) * TC) : (c * TC);
    {
        const float* src = dbl + ((size_t)b * SEQ + lbase) * 48;
        int nf4 = TC * 12;
        for (int i = t; i < nf4; i += 256)
            *(float4*)&sdbl[i * 4] = *(const float4*)(src + i * 4);
    }

    float A2[16], wdt[16];
    const float* ap = Alog + (size_t)d * NST;
    const float* wp = dtw + (size_t)d * NST;
    #pragma unroll
    for (int n = 0; n < 16; n++) { A2[n] = -__expf(ap[n]) * LOG2E; wdt[n] = wp[n]; }
    float bdt = dtb[d];
    float Dd = Dp[d];
    bool fast = true;
    #pragma unroll
    for (int n = 0; n < 16; n++)
        fast = fast && (fabsf(A2[n] - (n + 1) * A2[0]) < 1e-3f);

    size_t NCH = (size_t)nb * 16384;
    size_t base = (size_t)c * NCH + ((size_t)b * 1024 + d) * 16;
    float h[16];
    #pragma unroll
    for (int n = 0; n < 16; n += 4)
        *(float4*)&h[n] = *(const float4*)&hin[base + n];

    int lstep = dir ? -1 : 1;
    int l0 = dir ? (lbase + TC - 1) : lbase;
    size_t row0 = (size_t)b * SEQ + l0;
    const u16* up = xcp + row0 * 2048 + d;
    const float* zp = xz + row0 * 2048 + D_INNER + d;
    u16* yp = (u16*)(xz + row0 * 2048) + d;
    ptrdiff_t ups = (ptrdiff_t)lstep * 2048;
    ptrdiff_t zps = (ptrdiff_t)lstep * 2048;
    ptrdiff_t yps = (ptrdiff_t)lstep * 4096;   // u16 pitch of a 2048-float row
    const float* dr = sdbl + (dir ? (TC - 1) * 48 : 0);
    ptrdiff_t drs = (ptrdiff_t)lstep * 48;

    __syncthreads();

    auto body = [&](auto FC) {
        constexpr bool F = decltype(FC)::value;
        #pragma unroll 2
        for (int s = 0; s < TC; s++) {
            float dl[16], B[16], Cv[16];
            #pragma unroll
            for (int n = 0; n < 16; n += 4) {
                *(float4*)&dl[n] = *(const float4*)(dr + n);
                *(float4*)&B[n]  = *(const float4*)(dr + 16 + n);
                *(float4*)&Cv[n] = *(const float4*)(dr + 32 + n);
            }
            float u = bf2f(up[0]) + bf2f(up[D_INNER]);
            float acc = bdt;
            #pragma unroll
            for (int n = 0; n < 16; n++) acc += dl[n] * wdt[n];
            float dt = (acc > 20.0f) ? acc : __logf(1.0f + __expf(acc));
            float dtu = dt * u;
            float dA[16];
            if (F) {
                dA_pow(exp2f(A2[0] * dt), dA);
            } else {
                #pragma unroll
                for (int n = 0; n < 16; n++) dA[n] = exp2f(A2[n] * dt);
            }
            #pragma unroll
            for (int n = 0; n < 16; n++)
                h[n] = h[n] * dA[n] + dtu * B[n];

            float p0 = h[0]*Cv[0] + h[1]*Cv[1] + h[2]*Cv[2] + h[3]*Cv[3];
            float p1 = h[4]*Cv[4] + h[5]*Cv[5] + h[6]*Cv[6] + h[7]*Cv[7];
            float p2 = h[8]*Cv[8] + h[9]*Cv[9] + h[10]*Cv[10] + h[11]*Cv[11];
            float p3 = h[12]*Cv[12] + h[13]*Cv[13] + h[14]*Cv[14] + h[15]*Cv[15];

            float z = *zp;
            float g = z / (1.0f + __expf(-z));
            float y = ((p0 + p1) + (p2 + p3) + u * Dd) * g;

            u16 hi = f2bf(y);
            yp[0] = hi;
            yp[D_INNER] = f2bf(y - bf2f(hi));

            dr += drs; up += ups; zp += zps; yp += yps;
        }
    };
    if (fast) body(TrueT{}); else body(FalseT{});
}

// ---------------- host launch --------------------------------------------
extern "C" void kernel_launch(void* const* d_in, const int* in_sizes, int n_in,
                              void* d_out, int out_size, void* d_ws, size_t ws_size,
                              hipStream_t stream) {
    const float* input = (const float*)d_in[0];
    float* out = (float*)d_out;

    const size_t phfix = (size_t)2 * 256 * 16384 * 4;                 // 33.6 MB
    const size_t perb  = (size_t)2048 * (256 + 2048 + 1024 + 48) * 4; // 27.7 MB
    const size_t wspl  = (size_t)(2048 * 512 + 256 * 2048 + 128 * 2048) * 2;
    int nb = 4;                       // out_proj partials (R*4096 B) fit P+H
    while (nb > 1 && phfix + (size_t)nb * perb + wspl > ws_size) nb >>= 1;
    const int NC = 256 / nb;
    const int TC = SEQ / NC;
    const int R = nb * SEQ;
    const int NCH = nb * 16384;

    float* P    = (float*)d_ws;        // xproj partials / out_proj partials / scan P
    float* H    = P + (size_t)256 * 16384;
    float* xnf  = H + (size_t)256 * 16384;
    float* xz   = xnf + (size_t)R * D_MODEL;
    float* xcyf = xz  + (size_t)R * 2 * D_INNER;
    float* dbl  = xcyf + (size_t)R * D_INNER;
    u16*  winp  = (u16*)(dbl + (size_t)R * 48);
    u16*  woutp = winp + (size_t)2048 * 512;
    u16*  xpp   = woutp + (size_t)256 * 2048;   // padded to 128 rows (zeros)
    u16*  xnp   = (u16*)xnf;
    u16*  xcp   = (u16*)xcyf;

    for (int dir = 0; dir < 2; dir++) {
        int o = 1 + dir * 10;
        const float* nw   = (const float*)d_in[o + 0];
        const float* win  = (const float*)d_in[o + 1];
        const float* cw   = (const float*)d_in[o + 2];
        const float* cb   = (const float*)d_in[o + 3];
        const float* xp   = (const float*)d_in[o + 4];
        const float* dtw  = (const float*)d_in[o + 5];
        const float* dtbv = (const float*)d_in[o + 6];
        const float* Alog = (const float*)d_in[o + 7];
        const float* Dp   = (const float*)d_in[o + 8];
        const float* wout = (const float*)d_in[o + 9];

        wsplit_k<<<2048 * 256 / 256, 256, 0, stream>>>(win, winp, D_MODEL);
        wsplit_k<<<256 * 1024 / 256, 256, 0, stream>>>(wout, woutp, D_INNER);
        wsplit_pad_k<<<128 * 1024 / 256, 256, 0, stream>>>(xp, xpp, D_INNER, 48);

        for (int b0 = 0; b0 < 8; b0 += nb) {
            const float* xin = input + (size_t)b0 * SEQ * D_MODEL;
            float* cout = out + (size_t)b0 * SEQ * 2 * D_MODEL;

            rmsnorm_k<<<R, 256, 0, stream>>>(xin, nw, xnp);
            // in_proj: xz[R,2048] = xn * win^T, K'=768 (24 tiles)
            gemm_mfma2<<<dim3(R / 256, 8, 1), 512, 0, stream>>>(
                xnp, 512, winp, 512, xz, 2 * D_INNER, D_MODEL, 3 * D_MODEL, 0,
                2 * D_INNER);
            conv_silu_k<<<R, 256, 0, stream>>>(xz, cw, cb, xcp, dir);
            // x_proj: partials[8][R,48] = xc * xp^T, K'=3072, split-K=8
            gemm_mfma<<<dim3(R / 128, 1, 8), 256, 0, stream>>>(
                xcp, 2048, xpp, 2048, P, 48, D_INNER, 384, (size_t)R * 48, 48);
            reduce_dbl_k<<<R * 48 / 256, 256, 0, stream>>>(P, dbl, (size_t)R * 48);
            scan_p1<<<NC * nb * 4, 256, 0, stream>>>(
                xcp, dbl, dtw, dtbv, Alog, P, H, nb, TC, dir);
            scan_p2<<<NCH / 256, 256, 0, stream>>>(P, H, NCH, NC);
            scan_p3<<<NC * nb * 4, 256, 0, stream>>>(
                xcp, dbl, dtw, dtbv, xz, Alog, Dp, H, nb, TC, dir);
            // out_proj: y_pair * wout^T, K'=3072, split-K=4 (24 tiles each)
            gemm_mfma2<<<dim3(R / 256, 1, 4), 512, 0, stream>>>(
                (const u16*)xz, 4096, woutp, 2048, P, 256, D_INNER, 768,
                (size_t)R * 256, 256);
            reduce_out_k<<<R * 64 / 256, 256, 0, stream>>>(
                P, xin, cout, R, dir * D_MODEL);
        }
    }
}

// Round 3
// 912.341 us; speedup vs baseline: 1.0877x; 1.0877x over previous
//
#include <hip/hip_runtime.h>

typedef unsigned short u16;
typedef __bf16 bf16x8 __attribute__((ext_vector_type(8)));
typedef float f32x4 __attribute__((ext_vector_type(4)));

#define D_MODEL 256
#define D_INNER 1024
#define NST     16
#define SEQ     2048
#define LOG2E   1.4426950408889634f

struct TrueT  { static constexpr bool value = true;  };
struct FalseT { static constexpr bool value = false; };

static __device__ __forceinline__ float bf2f(u16 u) {
    union { float f; unsigned v; } x; x.v = ((unsigned)u) << 16; return x.f;
}
static __device__ __forceinline__ u16 f2bf(float f) {
    union { float f; unsigned u; } x; x.f = f;
    unsigned r = 0x7FFF + ((x.u >> 16) & 1);
    return (u16)((x.u + r) >> 16);
}

// async global->LDS, 16B per lane, LDS dest = wave-uniform base + lane*16
#define GLOAD_LDS16(g, l)                                            \
    __builtin_amdgcn_global_load_lds(                                \
        (const __attribute__((address_space(1))) void*)(g),          \
        (__attribute__((address_space(3))) void*)(l), 16, 0, 0)

// dA[n] = e1^(n+1), n=0..15, via binary decomposition (16 muls, depth ~5)
static __device__ __forceinline__ void dA_pow(float e1, float* dA) {
    float e2 = e1 * e1, e3 = e2 * e1, e4 = e2 * e2;
    float e8 = e4 * e4, e12 = e8 * e4;
    dA[0] = e1;       dA[1] = e2;       dA[2] = e3;       dA[3] = e4;
    dA[4] = e4 * e1;  dA[5] = e4 * e2;  dA[6] = e4 * e3;  dA[7] = e8;
    dA[8] = e8 * e1;  dA[9] = e8 * e2;  dA[10] = e8 * e3; dA[11] = e12;
    dA[12] = e12 * e1; dA[13] = e12 * e2; dA[14] = e12 * e3; dA[15] = e8 * e8;
}

// ---- RMSNorm -> split-bf16 pair output: row = [256 hi | 256 lo] u16 ----
__global__ __launch_bounds__(256) void rmsnorm_k(const float* __restrict__ x,
                                                 const float* __restrict__ w,
                                                 u16* __restrict__ xnp) {
    int row = blockIdx.x, t = threadIdx.x;
    float v = x[(size_t)row * D_MODEL + t];
    float s = v * v;
    #pragma unroll
    for (int o = 32; o; o >>= 1) s += __shfl_xor(s, o, 64);
    __shared__ float red[4];
    if ((t & 63) == 0) red[t >> 6] = s;
    __syncthreads();
    float tot = red[0] + red[1] + red[2] + red[3];
    float scale = rsqrtf(tot * (1.0f / D_MODEL) + 1e-5f);
    float xv = v * scale * w[t];
    u16 hi = f2bf(xv);
    u16 lo = f2bf(xv - bf2f(hi));
    xnp[(size_t)row * 512 + t] = hi;
    xnp[(size_t)row * 512 + 256 + t] = lo;
}

// ---- weight split: src[N*K] f32 -> dst[N][2K] bf16 (hi | lo) -----------
__global__ __launch_bounds__(256) void wsplit_k(const float* __restrict__ src,
                                                u16* __restrict__ dst, int K) {
    int i = blockIdx.x * 256 + threadIdx.x;
    int n = i / K, k = i - n * K;
    float v = src[i];
    u16 hi = f2bf(v);
    u16 lo = f2bf(v - bf2f(hi));
    dst[(size_t)n * 2 * K + k] = hi;
    dst[(size_t)n * 2 * K + K + k] = lo;
}

// ---- weight split with zero-padded rows (for x_proj: 48 real -> 128) ----
__global__ __launch_bounds__(256) void wsplit_pad_k(const float* __restrict__ src,
                                                    u16* __restrict__ dst, int K,
                                                    int Nreal) {
    int i = blockIdx.x * 256 + threadIdx.x;
    int n = i / K, k = i - n * K;
    float v = 0.0f;
    if (n < Nreal) v = src[i];
    u16 hi = f2bf(v);
    u16 lo = f2bf(v - bf2f(hi));
    dst[(size_t)n * 2 * K + k] = hi;
    dst[(size_t)n * 2 * K + K + k] = lo;
}

// ---- split-bf16 MFMA GEMM, 128x128 tile (x_proj N=48 masked; out_proj) --
__global__ __launch_bounds__(256) void gemm_mfma(const u16* __restrict__ Ap, int lda,
                                                 const u16* __restrict__ Wp, int ldw,
                                                 float* __restrict__ C, int ldc,
                                                 int KL, int kslice, size_t zstride,
                                                 int Nreal) {
    __shared__ u16 As[128][64];
    __shared__ u16 Ws[128][64];
    const int m0 = blockIdx.x * 128, n0 = blockIdx.y * 128;
    const int tid = threadIdx.x;
    const int wave = tid >> 6, lane = tid & 63;
    const int wm = (wave >> 1) * 64, wn = (wave & 1) * 64;
    const int lm = lane & 15, quad = lane >> 4;

    const int srow = lane >> 3;                // == row & 7
    const int schunk = (lane & 7) ^ srow;      // swizzled source 16B chunk
    const int rloc = wave * 8 + srow;

    f32x4 acc[4][4] = {};

    const int kb0 = blockIdx.z * kslice;
    for (int k0 = kb0; k0 < kb0 + kslice; k0 += 64) {
        int t = k0 / KL;
        int ko = k0 - t * KL;
        int ka = ko + (t == 2 ? KL : 0) + schunk * 8;
        int kw = ko + (t == 1 ? KL : 0) + schunk * 8;
        #pragma unroll
        for (int p = 0; p < 4; p++) {
            int row = p * 32 + rloc;
            GLOAD_LDS16(Ap + (size_t)(m0 + row) * lda + ka,
                        &As[p * 32 + wave * 8][0]);
            GLOAD_LDS16(Wp + (size_t)(n0 + row) * ldw + kw,
                        &Ws[p * 32 + wave * 8][0]);
        }
        __syncthreads();
        const int sc = lm & 7;
        #pragma unroll
        for (int kk = 0; kk < 2; kk++) {
            const int ch = ((kk << 2) | quad) ^ sc;   // undo swizzle
            bf16x8 af[4], bv[4];
            #pragma unroll
            for (int i = 0; i < 4; i++)
                af[i] = *(const bf16x8*)&As[wm + i * 16 + lm][ch * 8];
            #pragma unroll
            for (int j = 0; j < 4; j++)
                bv[j] = *(const bf16x8*)&Ws[wn + j * 16 + lm][ch * 8];
            #pragma unroll
            for (int i = 0; i < 4; i++)
                #pragma unroll
                for (int j = 0; j < 4; j++)
                    acc[i][j] = __builtin_amdgcn_mfma_f32_16x16x32_bf16(
                        af[i], bv[j], acc[i][j], 0, 0, 0);
        }
        __syncthreads();
    }

    float* Cz = C + zstride * blockIdx.z;
    #pragma unroll
    for (int i = 0; i < 4; i++)
        #pragma unroll
        for (int j = 0; j < 4; j++)
            #pragma unroll
            for (int r = 0; r < 4; r++) {
                int mrow = m0 + wm + i * 16 + quad * 4 + r;
                int ncol = n0 + wn + j * 16 + lm;
                if (ncol < Nreal)
                    Cz[(size_t)mrow * ldc + ncol] = acc[i][j][r];
            }
}

// ---- 256x256 tile, BK=32, 8-wave, 3-deep LDS ring, counted vmcnt --------
// T3+T4 schedule: while computing tile t (2 phases), tile t+1 is landed and
// tile t+2 is in flight (4 loads/thread). End-of-tile s_waitcnt vmcnt(4)
// guarantees t+1 landed (in-order vmem retirement) without draining t+2.
// LDS rows are 64B (32 u16), 4 chunks of 16B. Swizzle: LDS chunk c of row r
// holds global chunk c ^ f(r), f(r) = (r&3) ^ ((r>>2)&3).  This makes each
// wave's 64-lane fragment read a BIJECTION onto the 64 chunks of its 16-row
// group -> every bank gets exactly 8 balanced accesses (conflict-free).
// Applied inversely on the global source (LDS dest of gload_lds is linear).
// Requires: kslice % 32 == 0, NT = kslice/32 >= 2, M % 256 == 0,
//           Wp has >= gridDim.y*256 valid rows.
__global__ __launch_bounds__(512, 2) void gemm_mfma2(const u16* __restrict__ Ap, int lda,
                                                     const u16* __restrict__ Wp, int ldw,
                                                     float* __restrict__ C, int ldc,
                                                     int KL, int kslice, size_t zstride,
                                                     int Nreal) {
    __shared__ u16 As[3][256][32];
    __shared__ u16 Ws[3][256][32];
    const int m0 = blockIdx.x * 256, n0 = blockIdx.y * 256;
    const int tid = threadIdx.x;
    const int wave = tid >> 6, lane = tid & 63;
    const int wm = (wave >> 2) * 128, wn = (wave & 3) * 64;
    const int lm = lane & 15, quad = lane >> 4;

    // staging: per instr, wave covers 16 rows x 64B; lane -> row wave*16+(lane>>2),
    // LDS chunk (lane&3); global source chunk = (lane&3) ^ f(srow).
    const int srow = lane >> 2;
    const int schunk = (lane & 3) ^ ((srow ^ (srow >> 2)) & 3);
    // read-side: want global chunk 'quad' of row r=base16+lm ->
    // LDS chunk = quad ^ f(r) = quad ^ (lm&3) ^ ((lm>>2)&3)  (lane-constant)
    const int rsw = ((quad ^ lm ^ (lm >> 2)) & 3) * 8;
    const int KL2 = 2 * KL;

    const int NT = kslice / 32;
    const int kb0 = blockIdx.z * kslice;

    const u16* Arow = Ap + (size_t)(m0 + wave * 16 + srow) * lda + schunk * 8;
    const u16* Wrow = Wp + (size_t)(n0 + wave * 16 + srow) * ldw + schunk * 8;
    const size_t ldA = (size_t)128 * lda;
    const size_t ldW = (size_t)128 * ldw;
    u16* AsW = &As[0][wave * 16][0];   // + buf*8192 + half*4096
    u16* WsW = &Ws[0][wave * 16][0];

    f32x4 acc[8][4] = {};

    // k-offsets for tile ts (absolute k = kb0 + ts*32)
    auto koffs = [&](int ts, int& ka, int& kw) {
        int ks = kb0 + ts * 32;
        int t = (ks >= KL2) ? 2 : (ks >= KL ? 1 : 0);
        int ko = ks - t * KL;
        ka = ko + (t == 2 ? KL : 0);
        kw = ko + (t == 1 ? KL : 0);
    };

    // prologue: stage tiles 0 and 1 (grouped per tile for vmcnt counting)
    {
        int ka, kw;
        koffs(0, ka, kw);
        GLOAD_LDS16(Arow + ka, AsW);
        GLOAD_LDS16(Arow + ldA + ka, AsW + 4096);
        GLOAD_LDS16(Wrow + kw, WsW);
        GLOAD_LDS16(Wrow + ldW + kw, WsW + 4096);
        koffs(1, ka, kw);
        GLOAD_LDS16(Arow + ka, AsW + 8192);
        GLOAD_LDS16(Arow + ldA + ka, AsW + 8192 + 4096);
        GLOAD_LDS16(Wrow + kw, WsW + 8192);
        GLOAD_LDS16(Wrow + ldW + kw, WsW + 8192 + 4096);
    }
    asm volatile("s_waitcnt vmcnt(4)" ::: "memory");   // tile 0 landed
    __syncthreads();

    int cur = 0, stg = 2;                               // tt%3, (tt+2)%3
    for (int tt = 0; tt < NT; ++tt) {
        const u16* Ab = &As[cur][0][0];
        const u16* Wb = &Ws[cur][0][0];
        const bool pre = (tt + 2 < NT);
        int ka = 0, kw = 0;
        if (pre) koffs(tt + 2, ka, kw);

        bf16x8 bv[4], af[4];
        // ---- phase A: read B(all) + A frags 0..3; stage (tt+2) A halves ----
        #pragma unroll
        for (int j = 0; j < 4; j++) {
            int r = wn + j * 16 + lm;
            bv[j] = *(const bf16x8*)(Wb + r * 32 + rsw);
        }
        #pragma unroll
        for (int i = 0; i < 4; i++) {
            int r = wm + i * 16 + lm;
            af[i] = *(const bf16x8*)(Ab + r * 32 + rsw);
        }
        if (pre) {
            GLOAD_LDS16(Arow + ka, AsW + stg * 8192);
            GLOAD_LDS16(Arow + ldA + ka, AsW + stg * 8192 + 4096);
        }
        __syncthreads();
        __builtin_amdgcn_s_setprio(1);
        #pragma unroll
        for (int i = 0; i < 4; i++)
            #pragma unroll
            for (int j = 0; j < 4; j++)
                acc[i][j] = __builtin_amdgcn_mfma_f32_16x16x32_bf16(
                    af[i], bv[j], acc[i][j], 0, 0, 0);
        __builtin_amdgcn_s_setprio(0);
        __syncthreads();

        // ---- phase B: read A frags 4..7; stage (tt+2) W halves ----
        #pragma unroll
        for (int i = 0; i < 4; i++) {
            int r = wm + 64 + i * 16 + lm;
            af[i] = *(const bf16x8*)(Ab + r * 32 + rsw);
        }
        if (pre) {
            GLOAD_LDS16(Wrow + kw, WsW + stg * 8192);
            GLOAD_LDS16(Wrow + ldW + kw, WsW + stg * 8192 + 4096);
        }
        __syncthreads();
        __builtin_amdgcn_s_setprio(1);
        #pragma unroll
        for (int i = 0; i < 4; i++)
            #pragma unroll
            for (int j = 0; j < 4; j++)
                acc[4 + i][j] = __builtin_amdgcn_mfma_f32_16x16x32_bf16(
                    af[i], bv[j], acc[4 + i][j], 0, 0, 0);
        __builtin_amdgcn_s_setprio(0);
        // counted wait: all but tile (tt+2)'s 4 loads have landed => t+1 ready
        if (pre) asm volatile("s_waitcnt vmcnt(4)" ::: "memory");
        else     asm volatile("s_waitcnt vmcnt(0)" ::: "memory");
        __syncthreads();

        cur = (cur == 2) ? 0 : cur + 1;
        stg = (stg == 2) ? 0 : stg + 1;
    }

    float* Cz = C + zstride * blockIdx.z;
    #pragma unroll
    for (int i = 0; i < 8; i++)
        #pragma unroll
        for (int j = 0; j < 4; j++)
            #pragma unroll
            for (int r = 0; r < 4; r++) {
                int mrow = m0 + wm + i * 16 + quad * 4 + r;
                int ncol = n0 + wn + j * 16 + lm;
                if (ncol < Nreal)
                    Cz[(size_t)mrow * ldc + ncol] = acc[i][j][r];
            }
}

// ------ reduce 8 x_proj partials -> dbl[R*48] -----------------------------
__global__ __launch_bounds__(256) void reduce_dbl_k(const float* __restrict__ pbuf,
                                                    float* __restrict__ dbl,
                                                    size_t RS) {
    size_t e = (size_t)blockIdx.x * 256 + threadIdx.x;
    float v = 0.0f;
    #pragma unroll
    for (int z = 0; z < 8; z++) v += pbuf[z * RS + e];
    dbl[e] = v;
}

// ------ reduce 4 out_proj partials + residual -> out[m, coff + n] ---------
__global__ __launch_bounds__(256) void reduce_out_k(const float* __restrict__ pbuf,
                                                    const float* __restrict__ res,
                                                    float* __restrict__ out,
                                                    int M, int coff) {
    int idx = blockIdx.x * 256 + threadIdx.x;
    int m = idx >> 6, n4 = (idx & 63) * 4;
    size_t e = (size_t)m * 256 + n4;
    size_t stride = (size_t)M * 256;
    float4 v = *(const float4*)(res + e);
    #pragma unroll
    for (int s = 0; s < 4; s++) {
        float4 p = *(const float4*)(pbuf + s * stride + e);
        v.x += p.x; v.y += p.y; v.z += p.z; v.w += p.w;
    }
    *(float4*)(out + (size_t)m * 512 + coff + n4) = v;
}

// ---- depthwise causal conv + SiLU; out = split-bf16 pair ----------------
__global__ __launch_bounds__(256) void conv_silu_k(const float* __restrict__ xz,
                                                   const float* __restrict__ cw,
                                                   const float* __restrict__ cb,
                                                   u16* __restrict__ xcp, int dir) {
    int bx = blockIdx.x;
    int dgrp = bx & 3;
    int rowgrp = bx >> 2;
    int l0 = (rowgrp & (SEQ / 4 - 1)) * 4;
    int b = rowgrp >> 9;
    int d = dgrp * 256 + threadIdx.x;

    int base = dir ? l0 : (l0 - 3);
    float x[7];
    #pragma unroll
    for (int i = 0; i < 7; i++) {
        int lr = base + i;
        x[i] = (lr >= 0 && lr < SEQ)
             ? xz[((size_t)b * SEQ + lr) * (2 * D_INNER) + d] : 0.0f;
    }
    float w0 = cw[d * 4 + 0], w1 = cw[d * 4 + 1];
    float w2 = cw[d * 4 + 2], w3 = cw[d * 4 + 3];
    float bias = cb[d];

    #pragma unroll
    for (int li = 0; li < 4; li++) {
        float acc;
        if (dir == 0)
            acc = bias + w0 * x[li] + w1 * x[li + 1] + w2 * x[li + 2] + w3 * x[li + 3];
        else
            acc = bias + w3 * x[li] + w2 * x[li + 1] + w1 * x[li + 2] + w0 * x[li + 3];
        float s = acc / (1.0f + __expf(-acc));
        u16 hi = f2bf(s);
        u16 lo = f2bf(s - bf2f(hi));
        size_t row = (size_t)b * SEQ + l0 + li;
        xcp[row * 2048 + d] = hi;
        xcp[row * 2048 + D_INNER + d] = lo;
    }
}

// ---- scan phase 1: per-chunk H (h_in=0) and P; dbl staged in LDS --------
__global__ __launch_bounds__(256) void scan_p1(const u16* __restrict__ xcp,
                                               const float* __restrict__ dbl,
                                               const float* __restrict__ dtw,
                                               const float* __restrict__ dtb,
                                               const float* __restrict__ Alog,
                                               float* __restrict__ P,
                                               float* __restrict__ H,
                                               int nb, int TC, int dir) {
    __shared__ float sdbl[32 * 48];            // TC <= 32
    int t = threadIdx.x;
    int nblk4 = nb * 4;
    int c = blockIdx.x / nblk4;
    int rem = blockIdx.x - c * nblk4;
    int b = rem >> 2, dblk = rem & 3;
    int d = dblk * 256 + t;

    int lbase = dir ? (SEQ - (c + 1) * TC) : (c * TC);
    {
        const float* src = dbl + ((size_t)b * SEQ + lbase) * 48;
        int nf4 = TC * 12;
        for (int i = t; i < nf4; i += 256)
            *(float4*)&sdbl[i * 4] = *(const float4*)(src + i * 4);
    }

    float A2[16], wdt[16];
    const float* ap = Alog + (size_t)d * NST;
    const float* wp = dtw + (size_t)d * NST;
    #pragma unroll
    for (int n = 0; n < 16; n++) { A2[n] = -__expf(ap[n]) * LOG2E; wdt[n] = wp[n]; }
    float bdt = dtb[d];
    bool fast = true;
    #pragma unroll
    for (int n = 0; n < 16; n++)
        fast = fast && (fabsf(A2[n] - (n + 1) * A2[0]) < 1e-3f);

    float h[16] = {0,0,0,0,0,0,0,0,0,0,0,0,0,0,0,0};
    float S = 0.0f;

    int lstep = dir ? -1 : 1;
    int l0 = dir ? (lbase + TC - 1) : lbase;
    const u16* up = xcp + ((size_t)b * SEQ + l0) * 2048 + d;
    ptrdiff_t ups = (ptrdiff_t)lstep * 2048;
    const float* dr = sdbl + (dir ? (TC - 1) * 48 : 0);
    ptrdiff_t drs = (ptrdiff_t)lstep * 48;

    __syncthreads();

    auto body = [&](auto FC) {
        constexpr bool F = decltype(FC)::value;
        #pragma unroll 2
        for (int s = 0; s < TC; s++) {
            float dl[16], B[16];
            #pragma unroll
            for (int n = 0; n < 16; n += 4) {
                *(float4*)&dl[n] = *(const float4*)(dr + n);
                *(float4*)&B[n]  = *(const float4*)(dr + 16 + n);
            }
            float u = bf2f(up[0]) + bf2f(up[D_INNER]);
            float acc = bdt;
            #pragma unroll
            for (int n = 0; n < 16; n++) acc += dl[n] * wdt[n];
            float dt = (acc > 20.0f) ? acc : __logf(1.0f + __expf(acc));
            float dtu = dt * u;
            S += dt;
            float dA[16];
            if (F) {
                dA_pow(exp2f(A2[0] * dt), dA);
            } else {
                #pragma unroll
                for (int n = 0; n < 16; n++) dA[n] = exp2f(A2[n] * dt);
            }
            #pragma unroll
            for (int n = 0; n < 16; n++)
                h[n] = h[n] * dA[n] + dtu * B[n];
            dr += drs; up += ups;
        }
    };
    if (fast) body(TrueT{}); else body(FalseT{});

    size_t NCH = (size_t)nb * 16384;
    size_t base = (size_t)c * NCH + ((size_t)b * 1024 + d) * 16;
    float Pv[16];
    if (fast) {
        dA_pow(exp2f(A2[0] * S), Pv);
    } else {
        #pragma unroll
        for (int n = 0; n < 16; n++) Pv[n] = exp2f(A2[n] * S);
    }
    #pragma unroll
    for (int n = 0; n < 16; n += 4) {
        *(float4*)&H[base + n] = *(float4*)&h[n];
        *(float4*)&P[base + n] = *(float4*)&Pv[n];
    }
}

// ------- scan phase 2: combine chunk states; H repurposed as h_in --------
__global__ __launch_bounds__(256) void scan_p2(const float* __restrict__ P,
                                               float* __restrict__ H,
                                               int NCH, int NC) {
    size_t chain = (size_t)blockIdx.x * 256 + threadIdx.x;
    float h = 0.0f;
    for (int c = 0; c < NC; c++) {
        size_t i = (size_t)c * NCH + chain;
        float Hc = H[i], Pc = P[i];
        H[i] = h;
        h = Hc + Pc * h;
    }
}

// ---- scan phase 3: recurrence + silu(z) + y pair; dbl staged in LDS -----
__global__ __launch_bounds__(256) void scan_p3(const u16* __restrict__ xcp,
                                               const float* __restrict__ dbl,
                                               const float* __restrict__ dtw,
                                               const float* __restrict__ dtb,
                                               float* __restrict__ xz,
                                               const float* __restrict__ Alog,
                                               const float* __restrict__ Dp,
                                               const float* __restrict__ hin,
                                               int nb, int TC, int dir) {
    __shared__ float sdbl[32 * 48];
    int t = threadIdx.x;
    int nblk4 = nb * 4;
    int c = blockIdx.x / nblk4;
    int rem = blockIdx.x - c * nblk4;
    int b = rem >> 2, dblk = rem & 3;
    int d = dblk * 256 + t;

    int lbase = dir ? (SEQ - (c + 1) * TC) : (c * TC);
    {
        const float* src = dbl + ((size_t)b * SEQ + lbase) * 48;
        int nf4 = TC * 12;
        for (int i = t; i < nf4; i += 256)
            *(float4*)&sdbl[i * 4] = *(const float4*)(src + i * 4);
    }

    float A2[16], wdt[16];
    const float* ap = Alog + (size_t)d * NST;
    const float* wp = dtw + (size_t)d * NST;
    #pragma unroll
    for (int n = 0; n < 16; n++) { A2[n] = -__expf(ap[n]) * LOG2E; wdt[n] = wp[n]; }
    float bdt = dtb[d];
    float Dd = Dp[d];
    bool fast = true;
    #pragma unroll
    for (int n = 0; n < 16; n++)
        fast = fast && (fabsf(A2[n] - (n + 1) * A2[0]) < 1e-3f);

    size_t NCH = (size_t)nb * 16384;
    size_t base = (size_t)c * NCH + ((size_t)b * 1024 + d) * 16;
    float h[16];
    #pragma unroll
    for (int n = 0; n < 16; n += 4)
        *(float4*)&h[n] = *(const float4*)&hin[base + n];

    int lstep = dir ? -1 : 1;
    int l0 = dir ? (lbase + TC - 1) : lbase;
    size_t row0 = (size_t)b * SEQ + l0;
    const u16* up = xcp + row0 * 2048 + d;
    const float* zp = xz + row0 * 2048 + D_INNER + d;
    u16* yp = (u16*)(xz + row0 * 2048) + d;
    ptrdiff_t ups = (ptrdiff_t)lstep * 2048;
    ptrdiff_t zps = (ptrdiff_t)lstep * 2048;
    ptrdiff_t yps = (ptrdiff_t)lstep * 4096;   // u16 pitch of a 2048-float row
    const float* dr = sdbl + (dir ? (TC - 1) * 48 : 0);
    ptrdiff_t drs = (ptrdiff_t)lstep * 48;

    __syncthreads();

    auto body = [&](auto FC) {
        constexpr bool F = decltype(FC)::value;
        #pragma unroll 2
        for (int s = 0; s < TC; s++) {
            float dl[16], B[16], Cv[16];
            #pragma unroll
            for (int n = 0; n < 16; n += 4) {
                *(float4*)&dl[n] = *(const float4*)(dr + n);
                *(float4*)&B[n]  = *(const float4*)(dr + 16 + n);
                *(float4*)&Cv[n] = *(const float4*)(dr + 32 + n);
            }
            float u = bf2f(up[0]) + bf2f(up[D_INNER]);
            float acc = bdt;
            #pragma unroll
            for (int n = 0; n < 16; n++) acc += dl[n] * wdt[n];
            float dt = (acc > 20.0f) ? acc : __logf(1.0f + __expf(acc));
            float dtu = dt * u;
            float dA[16];
            if (F) {
                dA_pow(exp2f(A2[0] * dt), dA);
            } else {
                #pragma unroll
                for (int n = 0; n < 16; n++) dA[n] = exp2f(A2[n] * dt);
            }
            #pragma unroll
            for (int n = 0; n < 16; n++)
                h[n] = h[n] * dA[n] + dtu * B[n];

            float p0 = h[0]*Cv[0] + h[1]*Cv[1] + h[2]*Cv[2] + h[3]*Cv[3];
            float p1 = h[4]*Cv[4] + h[5]*Cv[5] + h[6]*Cv[6] + h[7]*Cv[7];
            float p2 = h[8]*Cv[8] + h[9]*Cv[9] + h[10]*Cv[10] + h[11]*Cv[11];
            float p3 = h[12]*Cv[12] + h[13]*Cv[13] + h[14]*Cv[14] + h[15]*Cv[15];

            float z = *zp;
            float g = z / (1.0f + __expf(-z));
            float y = ((p0 + p1) + (p2 + p3) + u * Dd) * g;

            u16 hi = f2bf(y);
            yp[0] = hi;
            yp[D_INNER] = f2bf(y - bf2f(hi));

            dr += drs; up += ups; zp += zps; yp += yps;
        }
    };
    if (fast) body(TrueT{}); else body(FalseT{});
}

// ---------------- host launch --------------------------------------------
extern "C" void kernel_launch(void* const* d_in, const int* in_sizes, int n_in,
                              void* d_out, int out_size, void* d_ws, size_t ws_size,
                              hipStream_t stream) {
    const float* input = (const float*)d_in[0];
    float* out = (float*)d_out;

    const size_t phfix = (size_t)2 * 256 * 16384 * 4;                 // 33.6 MB
    const size_t perb  = (size_t)2048 * (256 + 2048 + 1024 + 48) * 4; // 27.7 MB
    const size_t wspl  = (size_t)(2048 * 512 + 256 * 2048 + 128 * 2048) * 2;
    int nb = 4;                       // out_proj partials (R*4096 B) fit P+H
    while (nb > 1 && phfix + (size_t)nb * perb + wspl > ws_size) nb >>= 1;
    const int NC = 256 / nb;
    const int TC = SEQ / NC;
    const int R = nb * SEQ;
    const int NCH = nb * 16384;

    float* P    = (float*)d_ws;        // xproj partials / out_proj partials / scan P
    float* H    = P + (size_t)256 * 16384;
    float* xnf  = H + (size_t)256 * 16384;
    float* xz   = xnf + (size_t)R * D_MODEL;
    float* xcyf = xz  + (size_t)R * 2 * D_INNER;
    float* dbl  = xcyf + (size_t)R * D_INNER;
    u16*  winp  = (u16*)(dbl + (size_t)R * 48);
    u16*  woutp = winp + (size_t)2048 * 512;
    u16*  xpp   = woutp + (size_t)256 * 2048;   // padded to 128 rows (zeros)
    u16*  xnp   = (u16*)xnf;
    u16*  xcp   = (u16*)xcyf;

    for (int dir = 0; dir < 2; dir++) {
        int o = 1 + dir * 10;
        const float* nw   = (const float*)d_in[o + 0];
        const float* win  = (const float*)d_in[o + 1];
        const float* cw   = (const float*)d_in[o + 2];
        const float* cb   = (const float*)d_in[o + 3];
        const float* xp   = (const float*)d_in[o + 4];
        const float* dtw  = (const float*)d_in[o + 5];
        const float* dtbv = (const float*)d_in[o + 6];
        const float* Alog = (const float*)d_in[o + 7];
        const float* Dp   = (const float*)d_in[o + 8];
        const float* wout = (const float*)d_in[o + 9];

        wsplit_k<<<2048 * 256 / 256, 256, 0, stream>>>(win, winp, D_MODEL);
        wsplit_k<<<256 * 1024 / 256, 256, 0, stream>>>(wout, woutp, D_INNER);
        wsplit_pad_k<<<128 * 1024 / 256, 256, 0, stream>>>(xp, xpp, D_INNER, 48);

        for (int b0 = 0; b0 < 8; b0 += nb) {
            const float* xin = input + (size_t)b0 * SEQ * D_MODEL;
            float* cout = out + (size_t)b0 * SEQ * 2 * D_MODEL;

            rmsnorm_k<<<R, 256, 0, stream>>>(xin, nw, xnp);
            // in_proj: xz[R,2048] = xn * win^T, K'=768 (24 tiles)
            gemm_mfma2<<<dim3(R / 256, 8, 1), 512, 0, stream>>>(
                xnp, 512, winp, 512, xz, 2 * D_INNER, D_MODEL, 3 * D_MODEL, 0,
                2 * D_INNER);
            conv_silu_k<<<R, 256, 0, stream>>>(xz, cw, cb, xcp, dir);
            // x_proj: partials[8][R,48] = xc * xp^T, K'=3072, split-K=8
            gemm_mfma<<<dim3(R / 128, 1, 8), 256, 0, stream>>>(
                xcp, 2048, xpp, 2048, P, 48, D_INNER, 384, (size_t)R * 48, 48);
            reduce_dbl_k<<<R * 48 / 256, 256, 0, stream>>>(P, dbl, (size_t)R * 48);
            scan_p1<<<NC * nb * 4, 256, 0, stream>>>(
                xcp, dbl, dtw, dtbv, Alog, P, H, nb, TC, dir);
            scan_p2<<<NCH / 256, 256, 0, stream>>>(P, H, NCH, NC);
            scan_p3<<<NC * nb * 4, 256, 0, stream>>>(
                xcp, dbl, dtw, dtbv, xz, Alog, Dp, H, nb, TC, dir);
            // out_proj: y_pair * wout^T, K'=3072, split-K=4 (128-tile, 512 blks)
            gemm_mfma<<<dim3(R / 128, 2, 4), 256, 0, stream>>>(
                (const u16*)xz, 4096, woutp, 2048, P, 256, D_INNER, 768,
                (size_t)R * 256, 256);
            reduce_out_k<<<R * 64 / 256, 256, 0, stream>>>(
                P, xin, cout, R, dir * D_MODEL);
        }
    }
}

// Round 4
// 859.753 us; speedup vs baseline: 1.1542x; 1.0612x over previous
//
#include <hip/hip_runtime.h>

typedef unsigned short u16;
typedef __bf16 bf16x8 __attribute__((ext_vector_type(8)));
typedef float f32x4 __attribute__((ext_vector_type(4)));

#define D_MODEL 256
#define D_INNER 1024
#define NST     16
#define SEQ     2048
#define LOG2E   1.4426950408889634f

struct TrueT  { static constexpr bool value = true;  };
struct FalseT { static constexpr bool value = false; };

static __device__ __forceinline__ float bf2f(u16 u) {
    union { float f; unsigned v; } x; x.v = ((unsigned)u) << 16; return x.f;
}
static __device__ __forceinline__ u16 f2bf(float f) {
    union { float f; unsigned u; } x; x.f = f;
    unsigned r = 0x7FFF + ((x.u >> 16) & 1);
    return (u16)((x.u + r) >> 16);
}

// async global->LDS, 16B per lane, LDS dest = wave-uniform base + lane*16
#define GLOAD_LDS16(g, l)                                            \
    __builtin_amdgcn_global_load_lds(                                \
        (const __attribute__((address_space(1))) void*)(g),          \
        (__attribute__((address_space(3))) void*)(l), 16, 0, 0)

// dA[n] = e1^(n+1), n=0..15, via binary decomposition (16 muls, depth ~5)
static __device__ __forceinline__ void dA_pow(float e1, float* dA) {
    float e2 = e1 * e1, e3 = e2 * e1, e4 = e2 * e2;
    float e8 = e4 * e4, e12 = e8 * e4;
    dA[0] = e1;       dA[1] = e2;       dA[2] = e3;       dA[3] = e4;
    dA[4] = e4 * e1;  dA[5] = e4 * e2;  dA[6] = e4 * e3;  dA[7] = e8;
    dA[8] = e8 * e1;  dA[9] = e8 * e2;  dA[10] = e8 * e3; dA[11] = e12;
    dA[12] = e12 * e1; dA[13] = e12 * e2; dA[14] = e12 * e3; dA[15] = e8 * e8;
}

// ---- RMSNorm -> split-bf16 pair output: row = [256 hi | 256 lo] u16 ----
__global__ __launch_bounds__(256) void rmsnorm_k(const float* __restrict__ x,
                                                 const float* __restrict__ w,
                                                 u16* __restrict__ xnp) {
    int row = blockIdx.x, t = threadIdx.x;
    float v = x[(size_t)row * D_MODEL + t];
    float s = v * v;
    #pragma unroll
    for (int o = 32; o; o >>= 1) s += __shfl_xor(s, o, 64);
    __shared__ float red[4];
    if ((t & 63) == 0) red[t >> 6] = s;
    __syncthreads();
    float tot = red[0] + red[1] + red[2] + red[3];
    float scale = rsqrtf(tot * (1.0f / D_MODEL) + 1e-5f);
    float xv = v * scale * w[t];
    u16 hi = f2bf(xv);
    u16 lo = f2bf(xv - bf2f(hi));
    xnp[(size_t)row * 512 + t] = hi;
    xnp[(size_t)row * 512 + 256 + t] = lo;
}

// ---- weight split: src[N*K] f32 -> dst[N][2K] bf16 (hi | lo) -----------
__global__ __launch_bounds__(256) void wsplit_k(const float* __restrict__ src,
                                                u16* __restrict__ dst, int K) {
    int i = blockIdx.x * 256 + threadIdx.x;
    int n = i / K, k = i - n * K;
    float v = src[i];
    u16 hi = f2bf(v);
    u16 lo = f2bf(v - bf2f(hi));
    dst[(size_t)n * 2 * K + k] = hi;
    dst[(size_t)n * 2 * K + K + k] = lo;
}

// ---- weight split with zero-padded rows (for x_proj: 48 real -> 128) ----
__global__ __launch_bounds__(256) void wsplit_pad_k(const float* __restrict__ src,
                                                    u16* __restrict__ dst, int K,
                                                    int Nreal) {
    int i = blockIdx.x * 256 + threadIdx.x;
    int n = i / K, k = i - n * K;
    float v = 0.0f;
    if (n < Nreal) v = src[i];
    u16 hi = f2bf(v);
    u16 lo = f2bf(v - bf2f(hi));
    dst[(size_t)n * 2 * K + k] = hi;
    dst[(size_t)n * 2 * K + K + k] = lo;
}

// ---- split-bf16 MFMA GEMM, 128x128 tile (x_proj N=48 masked; out_proj) --
__global__ __launch_bounds__(256) void gemm_mfma(const u16* __restrict__ Ap, int lda,
                                                 const u16* __restrict__ Wp, int ldw,
                                                 float* __restrict__ C, int ldc,
                                                 int KL, int kslice, size_t zstride,
                                                 int Nreal) {
    __shared__ u16 As[128][64];
    __shared__ u16 Ws[128][64];
    const int m0 = blockIdx.x * 128, n0 = blockIdx.y * 128;
    const int tid = threadIdx.x;
    const int wave = tid >> 6, lane = tid & 63;
    const int wm = (wave >> 1) * 64, wn = (wave & 1) * 64;
    const int lm = lane & 15, quad = lane >> 4;

    const int srow = lane >> 3;                // == row & 7
    const int schunk = (lane & 7) ^ srow;      // swizzled source 16B chunk
    const int rloc = wave * 8 + srow;

    f32x4 acc[4][4] = {};

    const int kb0 = blockIdx.z * kslice;
    for (int k0 = kb0; k0 < kb0 + kslice; k0 += 64) {
        int t = k0 / KL;
        int ko = k0 - t * KL;
        int ka = ko + (t == 2 ? KL : 0) + schunk * 8;
        int kw = ko + (t == 1 ? KL : 0) + schunk * 8;
        #pragma unroll
        for (int p = 0; p < 4; p++) {
            int row = p * 32 + rloc;
            GLOAD_LDS16(Ap + (size_t)(m0 + row) * lda + ka,
                        &As[p * 32 + wave * 8][0]);
            GLOAD_LDS16(Wp + (size_t)(n0 + row) * ldw + kw,
                        &Ws[p * 32 + wave * 8][0]);
        }
        __syncthreads();
        const int sc = lm & 7;
        #pragma unroll
        for (int kk = 0; kk < 2; kk++) {
            const int ch = ((kk << 2) | quad) ^ sc;   // undo swizzle
            bf16x8 af[4], bv[4];
            #pragma unroll
            for (int i = 0; i < 4; i++)
                af[i] = *(const bf16x8*)&As[wm + i * 16 + lm][ch * 8];
            #pragma unroll
            for (int j = 0; j < 4; j++)
                bv[j] = *(const bf16x8*)&Ws[wn + j * 16 + lm][ch * 8];
            #pragma unroll
            for (int i = 0; i < 4; i++)
                #pragma unroll
                for (int j = 0; j < 4; j++)
                    acc[i][j] = __builtin_amdgcn_mfma_f32_16x16x32_bf16(
                        af[i], bv[j], acc[i][j], 0, 0, 0);
        }
        __syncthreads();
    }

    float* Cz = C + zstride * blockIdx.z;
    #pragma unroll
    for (int i = 0; i < 4; i++)
        #pragma unroll
        for (int j = 0; j < 4; j++)
            #pragma unroll
            for (int r = 0; r < 4; r++) {
                int mrow = m0 + wm + i * 16 + quad * 4 + r;
                int ncol = n0 + wn + j * 16 + lm;
                if (ncol < Nreal)
                    Cz[(size_t)mrow * ldc + ncol] = acc[i][j][r];
            }
}

// ---- 256x256 tile, BK=32, 8-wave, 3-deep LDS ring, RAW barriers ---------
// One raw s_barrier per K-tile; counted vmcnt(4) keeps next-next tile's
// loads in flight across the barrier (T3+T4).  __syncthreads is NOT used
// in the loop (it drains vmcnt(0) and kills the pipeline).
// Hazard safety: staging targets buf (t+2)%3, last read in tile t-1; the
// end-of-tile barrier separates those epochs (a wave's ds_reads are in regs
// before its MFMAs, which precede the barrier).
// LDS rows 64B (32 u16), 4x16B chunks; chunk swizzle c ^= (r ^ (r>>2)) & 3
// applied inversely on the global source, undone on the read side.
// Requires: kslice % 32 == 0, NT >= 2, M % 256 == 0, N-tiles fully valid.
__global__ __launch_bounds__(512, 2) void gemm_mfma2(const u16* __restrict__ Ap, int lda,
                                                     const u16* __restrict__ Wp, int ldw,
                                                     float* __restrict__ C, int ldc,
                                                     int KL, int kslice, size_t zstride,
                                                     int Nreal) {
    __shared__ u16 As[3][256][32];
    __shared__ u16 Ws[3][256][32];
    const int m0 = blockIdx.x * 256, n0 = blockIdx.y * 256;
    const int tid = threadIdx.x;
    const int wave = tid >> 6, lane = tid & 63;
    const int wm = (wave >> 2) * 128, wn = (wave & 3) * 64;
    const int lm = lane & 15, quad = lane >> 4;

    const int srow = lane >> 2;
    const int schunk = (lane & 3) ^ ((srow ^ (srow >> 2)) & 3);
    const int rsw = ((quad ^ lm ^ (lm >> 2)) & 3) * 8;   // lane-constant
    const int KL2 = 2 * KL;

    const int NT = kslice / 32;
    const int kb0 = blockIdx.z * kslice;

    const u16* Arow = Ap + (size_t)(m0 + wave * 16 + srow) * lda + schunk * 8;
    const u16* Wrow = Wp + (size_t)(n0 + wave * 16 + srow) * ldw + schunk * 8;
    const size_t ldA = (size_t)128 * lda;
    const size_t ldW = (size_t)128 * ldw;
    u16* AsW = &As[0][wave * 16][0];   // + buf*8192 (+4096 for rows 128..255)
    u16* WsW = &Ws[0][wave * 16][0];

    f32x4 acc[8][4] = {};

    auto koffs = [&](int ts, int& ka, int& kw) {
        int ks = kb0 + ts * 32;
        int t = (ks >= KL2) ? 2 : (ks >= KL ? 1 : 0);
        int ko = ks - t * KL;
        ka = ko + (t == 2 ? KL : 0);
        kw = ko + (t == 1 ? KL : 0);
    };

    // prologue: stage tiles 0 and 1 (per-tile groups of 4 for vmcnt math)
    {
        int ka, kw;
        koffs(0, ka, kw);
        GLOAD_LDS16(Arow + ka, AsW);
        GLOAD_LDS16(Arow + ldA + ka, AsW + 4096);
        GLOAD_LDS16(Wrow + kw, WsW);
        GLOAD_LDS16(Wrow + ldW + kw, WsW + 4096);
        koffs(1, ka, kw);
        GLOAD_LDS16(Arow + ka, AsW + 8192);
        GLOAD_LDS16(Arow + ldA + ka, AsW + 8192 + 4096);
        GLOAD_LDS16(Wrow + kw, WsW + 8192);
        GLOAD_LDS16(Wrow + ldW + kw, WsW + 8192 + 4096);
    }
    asm volatile("s_waitcnt vmcnt(4)" ::: "memory");   // tile 0 landed
    __builtin_amdgcn_s_barrier();
    __builtin_amdgcn_sched_barrier(0);

    int cur = 0, stg = 2;                               // tt%3, (tt+2)%3
    for (int tt = 0; tt < NT; ++tt) {
        const u16* Ab = &As[cur][0][0];
        const u16* Wb = &Ws[cur][0][0];
        const bool pre = (tt + 2 < NT);

        bf16x8 bv[4], af[8];
        #pragma unroll
        for (int j = 0; j < 4; j++)
            bv[j] = *(const bf16x8*)(Wb + (wn + j * 16 + lm) * 32 + rsw);
        #pragma unroll
        for (int i = 0; i < 8; i++)
            af[i] = *(const bf16x8*)(Ab + (wm + i * 16 + lm) * 32 + rsw);

        if (pre) {                       // stage tile tt+2 into ring slot stg
            int ka, kw;
            koffs(tt + 2, ka, kw);
            GLOAD_LDS16(Arow + ka, AsW + stg * 8192);
            GLOAD_LDS16(Arow + ldA + ka, AsW + stg * 8192 + 4096);
            GLOAD_LDS16(Wrow + kw, WsW + stg * 8192);
            GLOAD_LDS16(Wrow + ldW + kw, WsW + stg * 8192 + 4096);
        }

        __builtin_amdgcn_s_setprio(1);
        #pragma unroll
        for (int i = 0; i < 8; i++)
            #pragma unroll
            for (int j = 0; j < 4; j++)
                acc[i][j] = __builtin_amdgcn_mfma_f32_16x16x32_bf16(
                    af[i], bv[j], acc[i][j], 0, 0, 0);
        __builtin_amdgcn_s_setprio(0);

        if (pre)               asm volatile("s_waitcnt vmcnt(4)" ::: "memory");
        else if (tt == NT - 2) asm volatile("s_waitcnt vmcnt(0)" ::: "memory");
        if (tt != NT - 1) {
            __builtin_amdgcn_s_barrier();
            __builtin_amdgcn_sched_barrier(0);
        }

        cur = (cur == 2) ? 0 : cur + 1;
        stg = (stg == 2) ? 0 : stg + 1;
    }

    float* Cz = C + zstride * blockIdx.z;
    #pragma unroll
    for (int i = 0; i < 8; i++)
        #pragma unroll
        for (int j = 0; j < 4; j++)
            #pragma unroll
            for (int r = 0; r < 4; r++) {
                int mrow = m0 + wm + i * 16 + quad * 4 + r;
                int ncol = n0 + wn + j * 16 + lm;
                if (ncol < Nreal)
                    Cz[(size_t)mrow * ldc + ncol] = acc[i][j][r];
            }
}

// ------ reduce 8 x_proj partials -> dbl[R*48] -----------------------------
__global__ __launch_bounds__(256) void reduce_dbl_k(const float* __restrict__ pbuf,
                                                    float* __restrict__ dbl,
                                                    size_t RS) {
    size_t e = (size_t)blockIdx.x * 256 + threadIdx.x;
    float v = 0.0f;
    #pragma unroll
    for (int z = 0; z < 8; z++) v += pbuf[z * RS + e];
    dbl[e] = v;
}

// ------ reduce 4 out_proj partials + residual -> out[m, coff + n] ---------
__global__ __launch_bounds__(256) void reduce_out_k(const float* __restrict__ pbuf,
                                                    const float* __restrict__ res,
                                                    float* __restrict__ out,
                                                    int M, int coff) {
    int idx = blockIdx.x * 256 + threadIdx.x;
    int m = idx >> 6, n4 = (idx & 63) * 4;
    size_t e = (size_t)m * 256 + n4;
    size_t stride = (size_t)M * 256;
    float4 v = *(const float4*)(res + e);
    #pragma unroll
    for (int s = 0; s < 4; s++) {
        float4 p = *(const float4*)(pbuf + s * stride + e);
        v.x += p.x; v.y += p.y; v.z += p.z; v.w += p.w;
    }
    *(float4*)(out + (size_t)m * 512 + coff + n4) = v;
}

// ---- depthwise causal conv + SiLU; out = split-bf16 pair ----------------
__global__ __launch_bounds__(256) void conv_silu_k(const float* __restrict__ xz,
                                                   const float* __restrict__ cw,
                                                   const float* __restrict__ cb,
                                                   u16* __restrict__ xcp, int dir) {
    int bx = blockIdx.x;
    int dgrp = bx & 3;
    int rowgrp = bx >> 2;
    int l0 = (rowgrp & (SEQ / 4 - 1)) * 4;
    int b = rowgrp >> 9;
    int d = dgrp * 256 + threadIdx.x;

    int base = dir ? l0 : (l0 - 3);
    float x[7];
    #pragma unroll
    for (int i = 0; i < 7; i++) {
        int lr = base + i;
        x[i] = (lr >= 0 && lr < SEQ)
             ? xz[((size_t)b * SEQ + lr) * (2 * D_INNER) + d] : 0.0f;
    }
    float w0 = cw[d * 4 + 0], w1 = cw[d * 4 + 1];
    float w2 = cw[d * 4 + 2], w3 = cw[d * 4 + 3];
    float bias = cb[d];

    #pragma unroll
    for (int li = 0; li < 4; li++) {
        float acc;
        if (dir == 0)
            acc = bias + w0 * x[li] + w1 * x[li + 1] + w2 * x[li + 2] + w3 * x[li + 3];
        else
            acc = bias + w3 * x[li] + w2 * x[li + 1] + w1 * x[li + 2] + w0 * x[li + 3];
        float s = acc / (1.0f + __expf(-acc));
        u16 hi = f2bf(s);
        u16 lo = f2bf(s - bf2f(hi));
        size_t row = (size_t)b * SEQ + l0 + li;
        xcp[row * 2048 + d] = hi;
        xcp[row * 2048 + D_INNER + d] = lo;
    }
}

// ---- scan phase 1: per-chunk H (h_in=0) and P; dbl staged in LDS --------
__global__ __launch_bounds__(256) void scan_p1(const u16* __restrict__ xcp,
                                               const float* __restrict__ dbl,
                                               const float* __restrict__ dtw,
                                               const float* __restrict__ dtb,
                                               const float* __restrict__ Alog,
                                               float* __restrict__ P,
                                               float* __restrict__ H,
                                               int nb, int TC, int dir) {
    __shared__ float sdbl[32 * 48];            // TC <= 32
    int t = threadIdx.x;
    int nblk4 = nb * 4;
    int c = blockIdx.x / nblk4;
    int rem = blockIdx.x - c * nblk4;
    int b = rem >> 2, dblk = rem & 3;
    int d = dblk * 256 + t;

    int lbase = dir ? (SEQ - (c + 1) * TC) : (c * TC);
    {
        const float* src = dbl + ((size_t)b * SEQ + lbase) * 48;
        int nf4 = TC * 12;
        for (int i = t; i < nf4; i += 256)
            *(float4*)&sdbl[i * 4] = *(const float4*)(src + i * 4);
    }

    float A2[16], wdt[16];
    const float* ap = Alog + (size_t)d * NST;
    const float* wp = dtw + (size_t)d * NST;
    #pragma unroll
    for (int n = 0; n < 16; n++) { A2[n] = -__expf(ap[n]) * LOG2E; wdt[n] = wp[n]; }
    float bdt = dtb[d];
    bool fast = true;
    #pragma unroll
    for (int n = 0; n < 16; n++)
        fast = fast && (fabsf(A2[n] - (n + 1) * A2[0]) < 1e-3f);

    float h[16] = {0,0,0,0,0,0,0,0,0,0,0,0,0,0,0,0};
    float S = 0.0f;

    int lstep = dir ? -1 : 1;
    int l0 = dir ? (lbase + TC - 1) : lbase;
    const u16* up = xcp + ((size_t)b * SEQ + l0) * 2048 + d;
    ptrdiff_t ups = (ptrdiff_t)lstep * 2048;
    const float* dr = sdbl + (dir ? (TC - 1) * 48 : 0);
    ptrdiff_t drs = (ptrdiff_t)lstep * 48;

    __syncthreads();

    auto body = [&](auto FC) {
        constexpr bool F = decltype(FC)::value;
        #pragma unroll 2
        for (int s = 0; s < TC; s++) {
            float dl[16], B[16];
            #pragma unroll
            for (int n = 0; n < 16; n += 4) {
                *(float4*)&dl[n] = *(const float4*)(dr + n);
                *(float4*)&B[n]  = *(const float4*)(dr + 16 + n);
            }
            float u = bf2f(up[0]) + bf2f(up[D_INNER]);
            float acc = bdt;
            #pragma unroll
            for (int n = 0; n < 16; n++) acc += dl[n] * wdt[n];
            float dt = (acc > 20.0f) ? acc : __logf(1.0f + __expf(acc));
            float dtu = dt * u;
            S += dt;
            float dA[16];
            if (F) {
                dA_pow(exp2f(A2[0] * dt), dA);
            } else {
                #pragma unroll
                for (int n = 0; n < 16; n++) dA[n] = exp2f(A2[n] * dt);
            }
            #pragma unroll
            for (int n = 0; n < 16; n++)
                h[n] = h[n] * dA[n] + dtu * B[n];
            dr += drs; up += ups;
        }
    };
    if (fast) body(TrueT{}); else body(FalseT{});

    size_t NCH = (size_t)nb * 16384;
    size_t base = (size_t)c * NCH + ((size_t)b * 1024 + d) * 16;
    float Pv[16];
    if (fast) {
        dA_pow(exp2f(A2[0] * S), Pv);
    } else {
        #pragma unroll
        for (int n = 0; n < 16; n++) Pv[n] = exp2f(A2[n] * S);
    }
    #pragma unroll
    for (int n = 0; n < 16; n += 4) {
        *(float4*)&H[base + n] = *(float4*)&h[n];
        *(float4*)&P[base + n] = *(float4*)&Pv[n];
    }
}

// ------- scan phase 2: combine chunk states; H repurposed as h_in --------
__global__ __launch_bounds__(256) void scan_p2(const float* __restrict__ P,
                                               float* __restrict__ H,
                                               int NCH, int NC) {
    size_t chain = (size_t)blockIdx.x * 256 + threadIdx.x;
    float h = 0.0f;
    for (int c = 0; c < NC; c++) {
        size_t i = (size_t)c * NCH + chain;
        float Hc = H[i], Pc = P[i];
        H[i] = h;
        h = Hc + Pc * h;
    }
}

// ---- scan phase 3: recurrence + silu(z) + y pair; dbl staged in LDS -----
__global__ __launch_bounds__(256) void scan_p3(const u16* __restrict__ xcp,
                                               const float* __restrict__ dbl,
                                               const float* __restrict__ dtw,
                                               const float* __restrict__ dtb,
                                               float* __restrict__ xz,
                                               const float* __restrict__ Alog,
                                               const float* __restrict__ Dp,
                                               const float* __restrict__ hin,
                                               int nb, int TC, int dir) {
    __shared__ float sdbl[32 * 48];
    int t = threadIdx.x;
    int nblk4 = nb * 4;
    int c = blockIdx.x / nblk4;
    int rem = blockIdx.x - c * nblk4;
    int b = rem >> 2, dblk = rem & 3;
    int d = dblk * 256 + t;

    int lbase = dir ? (SEQ - (c + 1) * TC) : (c * TC);
    {
        const float* src = dbl + ((size_t)b * SEQ + lbase) * 48;
        int nf4 = TC * 12;
        for (int i = t; i < nf4; i += 256)
            *(float4*)&sdbl[i * 4] = *(const float4*)(src + i * 4);
    }

    float A2[16], wdt[16];
    const float* ap = Alog + (size_t)d * NST;
    const float* wp = dtw + (size_t)d * NST;
    #pragma unroll
    for (int n = 0; n < 16; n++) { A2[n] = -__expf(ap[n]) * LOG2E; wdt[n] = wp[n]; }
    float bdt = dtb[d];
    float Dd = Dp[d];
    bool fast = true;
    #pragma unroll
    for (int n = 0; n < 16; n++)
        fast = fast && (fabsf(A2[n] - (n + 1) * A2[0]) < 1e-3f);

    size_t NCH = (size_t)nb * 16384;
    size_t base = (size_t)c * NCH + ((size_t)b * 1024 + d) * 16;
    float h[16];
    #pragma unroll
    for (int n = 0; n < 16; n += 4)
        *(float4*)&h[n] = *(const float4*)&hin[base + n];

    int lstep = dir ? -1 : 1;
    int l0 = dir ? (lbase + TC - 1) : lbase;
    size_t row0 = (size_t)b * SEQ + l0;
    const u16* up = xcp + row0 * 2048 + d;
    const float* zp = xz + row0 * 2048 + D_INNER + d;
    u16* yp = (u16*)(xz + row0 * 2048) + d;
    ptrdiff_t ups = (ptrdiff_t)lstep * 2048;
    ptrdiff_t zps = (ptrdiff_t)lstep * 2048;
    ptrdiff_t yps = (ptrdiff_t)lstep * 4096;   // u16 pitch of a 2048-float row
    const float* dr = sdbl + (dir ? (TC - 1) * 48 : 0);
    ptrdiff_t drs = (ptrdiff_t)lstep * 48;

    __syncthreads();

    auto body = [&](auto FC) {
        constexpr bool F = decltype(FC)::value;
        #pragma unroll 2
        for (int s = 0; s < TC; s++) {
            float dl[16], B[16], Cv[16];
            #pragma unroll
            for (int n = 0; n < 16; n += 4) {
                *(float4*)&dl[n] = *(const float4*)(dr + n);
                *(float4*)&B[n]  = *(const float4*)(dr + 16 + n);
                *(float4*)&Cv[n] = *(const float4*)(dr + 32 + n);
            }
            float u = bf2f(up[0]) + bf2f(up[D_INNER]);
            float acc = bdt;
            #pragma unroll
            for (int n = 0; n < 16; n++) acc += dl[n] * wdt[n];
            float dt = (acc > 20.0f) ? acc : __logf(1.0f + __expf(acc));
            float dtu = dt * u;
            float dA[16];
            if (F) {
                dA_pow(exp2f(A2[0] * dt), dA);
            } else {
                #pragma unroll
                for (int n = 0; n < 16; n++) dA[n] = exp2f(A2[n] * dt);
            }
            #pragma unroll
            for (int n = 0; n < 16; n++)
                h[n] = h[n] * dA[n] + dtu * B[n];

            float p0 = h[0]*Cv[0] + h[1]*Cv[1] + h[2]*Cv[2] + h[3]*Cv[3];
            float p1 = h[4]*Cv[4] + h[5]*Cv[5] + h[6]*Cv[6] + h[7]*Cv[7];
            float p2 = h[8]*Cv[8] + h[9]*Cv[9] + h[10]*Cv[10] + h[11]*Cv[11];
            float p3 = h[12]*Cv[12] + h[13]*Cv[13] + h[14]*Cv[14] + h[15]*Cv[15];

            float z = *zp;
            float g = z / (1.0f + __expf(-z));
            float y = ((p0 + p1) + (p2 + p3) + u * Dd) * g;

            u16 hi = f2bf(y);
            yp[0] = hi;
            yp[D_INNER] = f2bf(y - bf2f(hi));

            dr += drs; up += ups; zp += zps; yp += yps;
        }
    };
    if (fast) body(TrueT{}); else body(FalseT{});
}

// ---------------- host launch --------------------------------------------
extern "C" void kernel_launch(void* const* d_in, const int* in_sizes, int n_in,
                              void* d_out, int out_size, void* d_ws, size_t ws_size,
                              hipStream_t stream) {
    const float* input = (const float*)d_in[0];
    float* out = (float*)d_out;

    const size_t phfix = (size_t)2 * 256 * 16384 * 4;                 // 33.6 MB
    const size_t perb  = (size_t)2048 * (256 + 2048 + 1024 + 48) * 4; // 27.7 MB
    const size_t wspl  = (size_t)(2048 * 512 + 256 * 2048 + 128 * 2048) * 2;
    int nb = 4;                       // out_proj partials (R*4096 B) fit P+H
    while (nb > 1 && phfix + (size_t)nb * perb + wspl > ws_size) nb >>= 1;
    const int NC = 256 / nb;
    const int TC = SEQ / NC;
    const int R = nb * SEQ;
    const int NCH = nb * 16384;

    float* P    = (float*)d_ws;        // xproj partials / out_proj partials / scan P
    float* H    = P + (size_t)256 * 16384;
    float* xnf  = H + (size_t)256 * 16384;
    float* xz   = xnf + (size_t)R * D_MODEL;
    float* xcyf = xz  + (size_t)R * 2 * D_INNER;
    float* dbl  = xcyf + (size_t)R * D_INNER;
    u16*  winp  = (u16*)(dbl + (size_t)R * 48);
    u16*  woutp = winp + (size_t)2048 * 512;
    u16*  xpp   = woutp + (size_t)256 * 2048;   // padded to 128 rows (zeros)
    u16*  xnp   = (u16*)xnf;
    u16*  xcp   = (u16*)xcyf;

    for (int dir = 0; dir < 2; dir++) {
        int o = 1 + dir * 10;
        const float* nw   = (const float*)d_in[o + 0];
        const float* win  = (const float*)d_in[o + 1];
        const float* cw   = (const float*)d_in[o + 2];
        const float* cb   = (const float*)d_in[o + 3];
        const float* xp   = (const float*)d_in[o + 4];
        const float* dtw  = (const float*)d_in[o + 5];
        const float* dtbv = (const float*)d_in[o + 6];
        const float* Alog = (const float*)d_in[o + 7];
        const float* Dp   = (const float*)d_in[o + 8];
        const float* wout = (const float*)d_in[o + 9];

        wsplit_k<<<2048 * 256 / 256, 256, 0, stream>>>(win, winp, D_MODEL);
        wsplit_k<<<256 * 1024 / 256, 256, 0, stream>>>(wout, woutp, D_INNER);
        wsplit_pad_k<<<128 * 1024 / 256, 256, 0, stream>>>(xp, xpp, D_INNER, 48);

        for (int b0 = 0; b0 < 8; b0 += nb) {
            const float* xin = input + (size_t)b0 * SEQ * D_MODEL;
            float* cout = out + (size_t)b0 * SEQ * 2 * D_MODEL;

            rmsnorm_k<<<R, 256, 0, stream>>>(xin, nw, xnp);
            // in_proj: xz[R,2048] = xn * win^T, K'=768 (24 tiles of 32)
            gemm_mfma2<<<dim3(R / 256, 8, 1), 512, 0, stream>>>(
                xnp, 512, winp, 512, xz, 2 * D_INNER, D_MODEL, 3 * D_MODEL, 0,
                2 * D_INNER);
            conv_silu_k<<<R, 256, 0, stream>>>(xz, cw, cb, xcp, dir);
            // x_proj: partials[8][R,48] = xc * xp^T, K'=3072, split-K=8
            gemm_mfma<<<dim3(R / 128, 1, 8), 256, 0, stream>>>(
                xcp, 2048, xpp, 2048, P, 48, D_INNER, 384, (size_t)R * 48, 48);
            reduce_dbl_k<<<R * 48 / 256, 256, 0, stream>>>(P, dbl, (size_t)R * 48);
            scan_p1<<<NC * nb * 4, 256, 0, stream>>>(
                xcp, dbl, dtw, dtbv, Alog, P, H, nb, TC, dir);
            scan_p2<<<NCH / 256, 256, 0, stream>>>(P, H, NCH, NC);
            scan_p3<<<NC * nb * 4, 256, 0, stream>>>(
                xcp, dbl, dtw, dtbv, xz, Alog, Dp, H, nb, TC, dir);
            // out_proj: y_pair * wout^T, K'=3072, split-K=4 (128-tile, 512 blks)
            gemm_mfma<<<dim3(R / 128, 2, 4), 256, 0, stream>>>(
                (const u16*)xz, 4096, woutp, 2048, P, 256, D_INNER, 768,
                (size_t)R * 256, 256);
            reduce_out_k<<<R * 64 / 256, 256, 0, stream>>>(
                P, xin, cout, R, dir * D_MODEL);
        }
    }
}